// Round 13
// baseline (14.065 us; speedup 1.0000x reference)
//
#include <hip/hip_runtime.h>
#include <hip/hip_bf16.h>

// out[n,d,oc,r] = logsumexp_ic( x[n,0,d,ic,r] + w[d,ic,oc,r] )
//              = log( sum_ic exp(x) * exp(w) )
// Batched GEMM over (d,r): K=IC=32 = one v_mfma_f32_16x16x32_bf16 per tile.
//
// R13: persistent-pair blocks. Grid = 64d x 8 = 512 blocks (2/CU, 8 waves/CU),
// each block = (d, ng-pair): TWO 16-row tiles in sequence. w staged ONCE for
// both tiles (w-exp redundancy halved); x double-buffered in LDS; all global
// loads issued up-front; stage(x1) overlaps compute(tile0); tile0 stores
// drain under tile1 compute (R9-proven overlap mechanism, 5.77 us steady).
// Thread roles / frag layouts identical to R10/R12 (verified, absmax 0.03125).

typedef __attribute__((ext_vector_type(8))) short bf16x8;
typedef __attribute__((ext_vector_type(4))) float f32x4;

constexpr int kD = 64, kIC = 32, kOC = 32, kR = 8;

__device__ __forceinline__ unsigned pk2(float a, float b) {
    __hip_bfloat162 h = __float22bfloat162_rn(make_float2(a, b));  // lo=a, hi=b
    unsigned r;
    __builtin_memcpy(&r, &h, 4);
    return r;
}

__global__ __launch_bounds__(256) void lse_kernel(
    const float* __restrict__ x, const float* __restrict__ w,
    float* __restrict__ out)
{
    // frag-ordered bf16: wsm [oc-tile u(2)][r(8)][lane(64)][slot(8)] = 16 KiB
    //                    xs  [buf(2)][r(8)][lane(64)][slot(8)]       = 16 KiB
    __shared__ __align__(16) unsigned short wsm[2 * 8 * 64 * 8];
    __shared__ __align__(16) unsigned short xs [2 * 8 * 64 * 8];

    const int t  = threadIdx.x;
    const int d  = blockIdx.x >> 3;
    const int pp = blockIdx.x & 7;        // ng-pair: tiles ng = 2*pp, 2*pp+1
    const int n0 = pp * 32;               // tile0 rows n0..n0+15, tile1 +16

    // ---------------- issue ALL global loads up front ----------------
    // w: thread (ol = t>>3 -> oc 0..31, chw = r-half, cqw): 8 float4
    const int cw = t & 7, chw = cw & 1, cqw = cw >> 1, ol = t >> 3;
    const float* wd = w + (size_t)d * (kIC * kOC * kR);
    float4 wv[8];
    #pragma unroll
    for (int a = 0; a < 4; ++a) {
        const int ic0 = 8 * a + 2 * cqw;
        wv[2*a]   = *reinterpret_cast<const float4*>(wd + (size_t)ic0 * 256 + ol * 8 + 4 * chw);
        wv[2*a+1] = *reinterpret_cast<const float4*>(wd + (size_t)(ic0 + 1) * 256 + ol * 8 + 4 * chw);
    }

    // x: thread (nlx = t>>4 -> row 0..15, e = r-half, icp): 4 float4 per tile
    const int cx = t & 15, e = cx & 1, icp = cx >> 1, nlx = t >> 4;
    const float* xr0 = x + (size_t)(n0 + nlx) * (kD * kIC * kR) + (size_t)d * (kIC * kR);
    const float* xr1 = xr0 + (size_t)16 * (kD * kIC * kR);
    float4 x0v[4], x1v[4];
    #pragma unroll
    for (int a = 0; a < 2; ++a) {
        const int ic0 = 16 * a + 2 * icp;
        x0v[2*a]   = *reinterpret_cast<const float4*>(xr0 + ic0 * 8 + 4 * e);
        x0v[2*a+1] = *reinterpret_cast<const float4*>(xr0 + ic0 * 8 + 8 + 4 * e);
        x1v[2*a]   = *reinterpret_cast<const float4*>(xr1 + ic0 * 8 + 4 * e);
        x1v[2*a+1] = *reinterpret_cast<const float4*>(xr1 + ic0 * 8 + 8 + 4 * e);
    }

    // ---------------- stage w ONCE: exp -> packed bf16 -> frag order ----------------
    {
        const int col = ol & 15, u = ol >> 4, s0 = 2 * cqw;
        #pragma unroll
        for (int a = 0; a < 4; ++a)
            #pragma unroll
            for (int j = 0; j < 4; ++j) {
                const int r = 4 * chw + j;
                const unsigned pk = pk2(
                    __expf(reinterpret_cast<const float*>(&wv[2*a])[j]),
                    __expf(reinterpret_cast<const float*>(&wv[2*a+1])[j]));
                *reinterpret_cast<unsigned*>(&wsm[((u * 8 + r) * 64 + a * 16 + col) * 8 + s0]) = pk;
            }
    }

    // x staging helper (buf selects LDS buffer)
    const int ig_lo = icp >> 2, s0x = 2 * (icp & 3);
    auto stage_x = [&](int buf, const float4* xcv) {
        #pragma unroll
        for (int a = 0; a < 2; ++a) {
            const int lane = (2 * a + ig_lo) * 16 + nlx;
            #pragma unroll
            for (int j = 0; j < 4; ++j) {
                const int r = 4 * e + j;
                const unsigned pk = pk2(
                    __expf(reinterpret_cast<const float*>(&xcv[2*a])[j]),
                    __expf(reinterpret_cast<const float*>(&xcv[2*a+1])[j]));
                *reinterpret_cast<unsigned*>(&xs[((buf * 8 + r) * 64 + lane) * 8 + s0x]) = pk;
            }
        }
    };

    stage_x(0, x0v);
    __syncthreads();

    // ---------------- compute / store helpers ----------------
    const int wave = t >> 6;
    const int wu  = wave & 1;          // oc-tile
    const int wrh = wave >> 1;         // r-half
    const int l   = t & 63;
    const int colL = l & 15, qL = l >> 4;

    auto compute = [&](int buf, f32x4* acc) {
        #pragma unroll
        for (int j = 0; j < 4; ++j) {
            const int r = wrh * 4 + j;
            bf16x8 av = *reinterpret_cast<const bf16x8*>(&xs [((buf * 8 + r) * 64 + l) * 8]);
            bf16x8 bv = *reinterpret_cast<const bf16x8*>(&wsm[((wu * 8 + r) * 64 + l) * 8]);
            f32x4 z = {0.f, 0.f, 0.f, 0.f};
            acc[j] = __builtin_amdgcn_mfma_f32_16x16x32_bf16(av, bv, z, 0, 0, 0);
        }
    };
    auto logstore = [&](int nt0, const f32x4* acc) {
        #pragma unroll
        for (int i = 0; i < 4; ++i) {
            const int n = nt0 + qL * 4 + i;
            float4 v;
            v.x = __logf(acc[0][i]); v.y = __logf(acc[1][i]);
            v.z = __logf(acc[2][i]); v.w = __logf(acc[3][i]);
            *reinterpret_cast<float4*>(out + (size_t)n * (kD * kOC * kR)
                + (size_t)d * (kOC * kR) + (size_t)(wu * 16 + colL) * 8 + wrh * 4) = v;
        }
    };

    // ---------------- pipelined tiles ----------------
    f32x4 acc0[4], acc1[4];
    compute(0, acc0);
    stage_x(1, x1v);        // overlaps MFMA/logstore of tile0 (disjoint buffer)
    logstore(n0, acc0);     // stores drain under tile1 compute
    __syncthreads();
    compute(1, acc1);
    logstore(n0 + 16, acc1);
}

extern "C" void kernel_launch(void* const* d_in, const int* in_sizes, int n_in,
                              void* d_out, int out_size, void* d_ws, size_t ws_size,
                              hipStream_t stream) {
    const float* x = (const float*)d_in[0];
    const float* w = (const float*)d_in[1];
    float* out = (float*)d_out;
    lse_kernel<<<dim3(kD * 8), 256, 0, stream>>>(x, w, out);
}

// Round 14
// 12.472 us; speedup vs baseline: 1.1278x; 1.1278x over previous
//
#include <hip/hip_runtime.h>

// out[n,d,oc,r] = logsumexp_ic( x[n,0,d,ic,r] + w[d,ic,oc,r] )
//              = log( sum_ic exp(x) * exp(w) )
// Batched GEMM over (d,r): K=IC=32 = one v_mfma_f32_16x16x32_bf16 per tile.
//
// R14 = R10 verbatim (session champion, 12.50 us). Five structural variants
// (intra-block pipeline x2, r-split, pair-blocks, cvt_pk VALU trim) all
// measured neutral-to-worse; reverting to the best configuration.
// Block = (d, 16 n): grid 64x16 = 1024 blocks = 4 blocks/CU = 16 waves/CU.
// LDS 24 KiB/block; 1 barrier; waves split (oc-tile, r-half); 4 MFMAs +
// 16 logs + 4 float4 stores per thread.

typedef __attribute__((ext_vector_type(8))) short bf16x8;
typedef __attribute__((ext_vector_type(4))) float f32x4;

constexpr int kD = 64, kIC = 32, kOC = 32, kR = 8;

__device__ __forceinline__ unsigned short f2bf(float f) {
    unsigned u = __builtin_bit_cast(unsigned, f);
    u += 0x7FFFu + ((u >> 16) & 1u);          // RTNE (inputs positive finite)
    return (unsigned short)(u >> 16);
}
__device__ __forceinline__ unsigned pk2(float a, float b) {
    return (unsigned)f2bf(a) | ((unsigned)f2bf(b) << 16);
}

__global__ __launch_bounds__(256) void lse_kernel(
    const float* __restrict__ x, const float* __restrict__ w,
    float* __restrict__ out)
{
    // frag-ordered bf16: wsm [oc-tile u(2)][r(8)][lane(64)][slot(8)] = 16 KiB
    //                    xs  [r(8)][lane(64)][slot(8)]               =  8 KiB
    __shared__ __align__(16) unsigned short wsm[2 * 8 * 64 * 8];
    __shared__ __align__(16) unsigned short xs [8 * 64 * 8];

    const int t  = threadIdx.x;
    const int d  = blockIdx.x;
    const int n0 = blockIdx.y * 16;

    // ---------------- issue all global loads up front ----------------
    // w: thread (ol = t>>3 -> oc 0..31, chw = r-half, cqw): 8 float4
    const int cw = t & 7, chw = cw & 1, cqw = cw >> 1, ol = t >> 3;
    const float* wd = w + (size_t)d * (kIC * kOC * kR);
    float4 wv[8];
    #pragma unroll
    for (int a = 0; a < 4; ++a) {
        const int ic0 = 8 * a + 2 * cqw;
        wv[2*a]   = *reinterpret_cast<const float4*>(wd + (size_t)ic0 * 256 + ol * 8 + 4 * chw);
        wv[2*a+1] = *reinterpret_cast<const float4*>(wd + (size_t)(ic0 + 1) * 256 + ol * 8 + 4 * chw);
    }

    // x: thread (nlx = t>>4 -> row 0..15, e = r-half, icp): 4 float4
    const int cx = t & 15, e = cx & 1, icp = cx >> 1, nlx = t >> 4;
    const float* xr = x + (size_t)(n0 + nlx) * (kD * kIC * kR) + (size_t)d * (kIC * kR);
    float4 xv[4];
    #pragma unroll
    for (int a = 0; a < 2; ++a) {
        const int ic0 = 16 * a + 2 * icp;
        xv[2*a]   = *reinterpret_cast<const float4*>(xr + ic0 * 8 + 4 * e);
        xv[2*a+1] = *reinterpret_cast<const float4*>(xr + ic0 * 8 + 8 + 4 * e);
    }

    // ---------------- stage w: exp -> bf16 pairs -> frag order ----------------
    {
        const int col = ol & 15, u = ol >> 4, s0 = 2 * cqw;
        #pragma unroll
        for (int a = 0; a < 4; ++a)
            #pragma unroll
            for (int j = 0; j < 4; ++j) {
                const int r = 4 * chw + j;
                const unsigned pk = pk2(
                    __expf(reinterpret_cast<const float*>(&wv[2*a])[j]),
                    __expf(reinterpret_cast<const float*>(&wv[2*a+1])[j]));
                *reinterpret_cast<unsigned*>(&wsm[((u * 8 + r) * 64 + a * 16 + col) * 8 + s0]) = pk;
            }
    }

    // ---------------- stage x: exp -> bf16 pairs -> frag order ----------------
    {
        const int ig_lo = icp >> 2;            // ic0 = 16a + 2*icp: g = 2a + ig_lo
        const int s0x = 2 * (icp & 3);
        #pragma unroll
        for (int a = 0; a < 2; ++a) {
            const int lane = (2 * a + ig_lo) * 16 + nlx;
            #pragma unroll
            for (int j = 0; j < 4; ++j) {
                const int r = 4 * e + j;
                const unsigned pk = pk2(
                    __expf(reinterpret_cast<const float*>(&xv[2*a])[j]),
                    __expf(reinterpret_cast<const float*>(&xv[2*a+1])[j]));
                *reinterpret_cast<unsigned*>(&xs[(r * 64 + lane) * 8 + s0x]) = pk;
            }
        }
    }

    __syncthreads();

    // ---------------- MFMA: wave (wu = oc-tile, wrh = r-half), 4 r, K=32 ----------------
    const int wave = t >> 6;
    const int wu  = wave & 1;
    const int wrh = wave >> 1;
    const int l   = t & 63;
    const int colL = l & 15, qL = l >> 4;

    f32x4 acc[4];
    #pragma unroll
    for (int j = 0; j < 4; ++j) {
        const int r = wrh * 4 + j;
        bf16x8 av = *reinterpret_cast<const bf16x8*>(&xs [(r * 64 + l) * 8]);
        bf16x8 bv = *reinterpret_cast<const bf16x8*>(&wsm[((wu * 8 + r) * 64 + l) * 8]);
        f32x4 z = {0.f, 0.f, 0.f, 0.f};
        acc[j] = __builtin_amdgcn_mfma_f32_16x16x32_bf16(av, bv, z, 0, 0, 0);
    }

    // ---------------- epilogue: log + float4 store ----------------
    // C/D: col = l&15, row = (l>>4)*4 + i;  r-quad contiguous at wrh*4
    #pragma unroll
    for (int i = 0; i < 4; ++i) {
        const int n = n0 + qL * 4 + i;
        float4 v;
        v.x = __logf(acc[0][i]); v.y = __logf(acc[1][i]);
        v.z = __logf(acc[2][i]); v.w = __logf(acc[3][i]);
        *reinterpret_cast<float4*>(out + (size_t)n * (kD * kOC * kR)
            + (size_t)d * (kOC * kR) + (size_t)(wu * 16 + colL) * 8 + wrh * 4) = v;
    }
}

extern "C" void kernel_launch(void* const* d_in, const int* in_sizes, int n_in,
                              void* d_out, int out_size, void* d_ws, size_t ws_size,
                              hipStream_t stream) {
    const float* x = (const float*)d_in[0];
    const float* w = (const float*)d_in[1];
    float* out = (float*)d_out;
    dim3 grid(kD, 16);
    lse_kernel<<<grid, 256, 0, stream>>>(x, w, out);
}